// Round 5
// baseline (815.197 us; speedup 1.0000x reference)
//
#include <hip/hip_runtime.h>
#include <hip/hip_fp16.h>

typedef float f32x4 __attribute__((ext_vector_type(4)));

#define N_NODES 100000
#define NBUK 391          // ceil(100000/256) coarse buckets of 256 nodes
#define BSHIFT 8
#define HBLK 256          // partition blocks for hist/bucketize (must match)

// ---------------- edge dtype detect: mode=1 -> int32 layout, mode=0 -> int64 (low/high words) ----
__global__ void k_detect(const int* __restrict__ ei, int* __restrict__ mode) {
    __shared__ int flag;
    if (threadIdx.x == 0) flag = 0;
    __syncthreads();
    int f = 0;
    for (int i = threadIdx.x; i < 4096; i += 256)
        if (ei[2 * i + 1] != 0) f = 1;
    if (f) flag = 1;   // benign race: all writers store 1
    __syncthreads();
    if (threadIdx.x == 0) *mode = flag;
}

// ---------------- coarse histogram: per-block LDS hist, NO global atomics ----------------
__global__ __launch_bounds__(256) void k_hist(const int* __restrict__ ei,
                                              const int* __restrict__ mode,
                                              int* __restrict__ gh, int E, int chunk) {
    __shared__ int hist[NBUK];
    int tid = threadIdx.x, k = blockIdx.x;
    for (int b = tid; b < NBUK; b += 256) hist[b] = 0;
    __syncthreads();
    int m = *mode;
    int e0 = k * chunk, e1 = min(E, e0 + chunk);
    for (int e = e0 + tid; e < e1; e += 256) {
        int d = m ? ei[E + e] : ei[2 * (E + e)];
        if ((unsigned)d >= N_NODES) d = 0;
        atomicAdd(&hist[d >> BSHIFT], 1);   // LDS atomic
    }
    __syncthreads();
    for (int b = tid; b < NBUK; b += 256) gh[k * NBUK + b] = hist[b];
}

// ---------------- per-bucket totals (391 blocks) ----------------
__global__ __launch_bounds__(256) void k_btot(const int* __restrict__ gh, int* __restrict__ btot) {
    __shared__ int s[256];
    int b = blockIdx.x, tid = threadIdx.x;
    s[tid] = gh[tid * NBUK + b];
    __syncthreads();
    for (int d = 128; d > 0; d >>= 1) {
        if (tid < d) s[tid] += s[tid + d];
        __syncthreads();
    }
    if (tid == 0) btot[b] = s[0];
}

// ---------------- scan of bucket totals -> bucket bases ----------------
__global__ void k_scan_btot(const int* __restrict__ btot, int* __restrict__ bbase,
                            int* __restrict__ rowptr, int E) {
    __shared__ int s[512];
    int tid = threadIdx.x;
    int v = (tid < NBUK) ? btot[tid] : 0;
    s[tid] = v;
    __syncthreads();
    for (int d = 1; d < 512; d <<= 1) {
        int t = (tid >= d) ? s[tid - d] : 0;
        __syncthreads();
        s[tid] += t;
        __syncthreads();
    }
    if (tid < NBUK) bbase[tid] = s[tid] - v;   // exclusive
    if (tid == 0) { bbase[NBUK] = E; rowptr[N_NODES] = E; }
}

// ---------------- per-bucket column scans: gh -> per-(block,bucket) write offsets (in place) ----
__global__ __launch_bounds__(256) void k_scan_cols(int* __restrict__ gh, const int* __restrict__ bbase) {
    __shared__ int s[256];
    int b = blockIdx.x, tid = threadIdx.x;
    int v = gh[tid * NBUK + b];
    s[tid] = v;
    __syncthreads();
    for (int d = 1; d < 256; d <<= 1) {
        int t = (tid >= d) ? s[tid - d] : 0;
        __syncthreads();
        s[tid] += t;
        __syncthreads();
    }
    gh[tid * NBUK + b] = bbase[b] + s[tid] - v;
}

// ---------------- bucketize: ranked scatter into coarse buckets, LDS cursors only ----------------
__global__ __launch_bounds__(256) void k_bucketize(const int* __restrict__ ei,
                                                   const int* __restrict__ mode,
                                                   const int* __restrict__ offs,
                                                   int2* __restrict__ bp, int E, int chunk) {
    __shared__ int cur[NBUK];
    int tid = threadIdx.x, k = blockIdx.x;
    for (int b = tid; b < NBUK; b += 256) cur[b] = offs[k * NBUK + b];
    __syncthreads();
    int m = *mode;
    int e0 = k * chunk, e1 = min(E, e0 + chunk);
    for (int e = e0 + tid; e < e1; e += 256) {
        int s, d;
        if (m) { s = ei[e]; d = ei[E + e]; }
        else   { s = ei[2 * e]; d = ei[2 * (E + e)]; }
        if ((unsigned)s >= N_NODES) s = 0;
        if ((unsigned)d >= N_NODES) d = 0;
        int pos = atomicAdd(&cur[d >> BSHIFT], 1);   // LDS atomic
        int2 p; p.x = s; p.y = d;
        bp[pos] = p;
    }
}

// ---------------- per-bucket CSR build: LDS counts/scan/cursors, writes rowptr+dinv+csr ----------
__global__ __launch_bounds__(256) void k_build_csr(const int2* __restrict__ bp,
                                                   const int* __restrict__ bbase,
                                                   int* __restrict__ rowptr,
                                                   float* __restrict__ dinv,
                                                   int* __restrict__ csr) {
    __shared__ int cnt[256];
    __shared__ int s[256];
    __shared__ int cur[256];
    int b = blockIdx.x, tid = threadIdx.x;
    int nb = b << BSHIFT;
    int estart = bbase[b], eend = bbase[b + 1];
    cnt[tid] = 0;
    __syncthreads();
    for (int e = estart + tid; e < eend; e += 256) {
        int2 p = bp[e];
        atomicAdd(&cnt[p.y - nb], 1);   // LDS atomic
    }
    __syncthreads();
    int v = cnt[tid];
    s[tid] = v;
    __syncthreads();
    for (int d = 1; d < 256; d <<= 1) {
        int t = (tid >= d) ? s[tid - d] : 0;
        __syncthreads();
        s[tid] += t;
        __syncthreads();
    }
    int excl = s[tid] - v;
    int node = nb + tid;
    if (node < N_NODES) {
        rowptr[node] = estart + excl;
        dinv[node] = rsqrtf((float)v + 1.0f);
    }
    cur[tid] = estart + excl;
    __syncthreads();
    for (int e = estart + tid; e < eend; e += 256) {
        int2 p = bp[e];
        int pos = atomicAdd(&cur[p.y - nb], 1);   // LDS atomic
        csr[pos] = p.x;
    }
}

// ---------------- GEMM1: H2[100000,32]fp16 = (X[100000,512] @ W[512,32]) * dinv ----------------
// thread = one row, all 32 cols. X staged in LDS (b32 reads, conflict-free).
// W read with lane-uniform indices -> compiler emits s_load (SMEM pipe, zero LDS traffic).
__global__ __launch_bounds__(128) void k_gemm1(const float* __restrict__ X,
                                               const float* __restrict__ W,
                                               const float* __restrict__ dinv,
                                               __half2* __restrict__ H2) {
    __shared__ float xs[128 * 65];
    int tid = threadIdx.x;
    long row0 = (long)blockIdx.x * 128;
    float acc[32];
#pragma unroll
    for (int c = 0; c < 32; c++) acc[c] = 0.f;

    for (int k0 = 0; k0 < 512; k0 += 64) {
        __syncthreads();
        // stage X tile: 128 rows x 64 k, coalesced (16 lanes cover one row's 64 k)
#pragma unroll
        for (int u = 0; u < 16; u++) {
            int idx = u * 128 + tid;
            int r = idx >> 4, j = idx & 15;
            long grow = row0 + r;
            f32x4 v = {0.f, 0.f, 0.f, 0.f};
            if (grow < N_NODES) v = *(const f32x4*)&X[grow * 512 + k0 + 4 * j];
            float* dp = &xs[r * 65 + 4 * j];
            dp[0] = v.x; dp[1] = v.y; dp[2] = v.z; dp[3] = v.w;
        }
        __syncthreads();
        const float* xr = &xs[tid * 65];
#pragma unroll
        for (int kk = 0; kk < 64; kk++) {
            float xk = xr[kk];
            const float* wr = &W[(long)(k0 + kk) * 32];   // lane-uniform -> s_load
#pragma unroll
            for (int c = 0; c < 32; c += 4) {
                f32x4 wv = *(const f32x4*)&wr[c];
                acc[c]     += xk * wv.x;
                acc[c + 1] += xk * wv.y;
                acc[c + 2] += xk * wv.z;
                acc[c + 3] += xk * wv.w;
            }
        }
    }
    long row = row0 + tid;
    if (row < N_NODES) {
        float dv = dinv[row];
        __half2* hp = &H2[row * 16];
#pragma unroll
        for (int c = 0; c < 16; c++)
            hp[c] = __floats2half2_rn(acc[2 * c] * dv, acc[2 * c + 1] * dv);
    }
}

// ---------------- agg half-pass: 16 feats (po*2..po*2+15), H half-slab is L2-resident ----------
// 8 lanes per node, each lane one half2 (2 feats). x = relu(dv*(sum H2[src]+H2[node])+b)
__global__ __launch_bounds__(256) void k_agg(const __half2* __restrict__ H2,
                                             const int* __restrict__ rowptr,
                                             const int* __restrict__ csr,
                                             const float* __restrict__ dinv,
                                             const float* __restrict__ bias,
                                             __half2* __restrict__ X2, int po) {
    int tid = threadIdx.x;
    int node = blockIdx.x * 32 + (tid >> 3);
    int l = tid & 7;
    int off = po + l;
    int e0 = rowptr[node], e1 = rowptr[node + 1];
    float ax = 0.f, ay = 0.f;
    for (int base = e0; base < e1; base += 8) {
        int idx = base + l;
        int sl = (idx < e1) ? csr[idx] : 0;   // coalesced 8-wide csr load
        int cnt = e1 - base;
        if (cnt >= 8) {
#pragma unroll
            for (int j = 0; j < 8; j++) {
                int s = __shfl(sl, j, 8);
                float2 v = __half22float2(H2[(long)s * 16 + off]);
                ax += v.x; ay += v.y;
            }
        } else {
            for (int j = 0; j < cnt; j++) {
                int s = __shfl(sl, j, 8);
                float2 v = __half22float2(H2[(long)s * 16 + off]);
                ax += v.x; ay += v.y;
            }
        }
    }
    float dv = dinv[node];
    float2 sf = __half22float2(H2[(long)node * 16 + off]);
    float2 bv = *(const float2*)&bias[2 * off];
    float vx = fmaxf(dv * (ax + sf.x) + bv.x, 0.f);
    float vy = fmaxf(dv * (ay + sf.y) + bv.y, 0.f);
    X2[(long)node * 16 + off] = __floats2half2_rn(vx, vy);
}

// ---------------- transform: H2out = (x @ W[32,32]) * dinv, W via uniform s_loads ----------------
__global__ __launch_bounds__(256) void k_mm(const __half2* __restrict__ X2,
                                            const float* __restrict__ W,
                                            const float* __restrict__ dinv,
                                            __half2* __restrict__ H2, int n) {
    int r = blockIdx.x * 256 + threadIdx.x;
    if (r >= n) return;
    float x[32];
#pragma unroll
    for (int i = 0; i < 16; i++) {
        float2 v = __half22float2(X2[(long)r * 16 + i]);
        x[2 * i] = v.x; x[2 * i + 1] = v.y;
    }
    float acc[32];
#pragma unroll
    for (int c = 0; c < 32; c++) acc[c] = 0.f;
#pragma unroll
    for (int k = 0; k < 32; k++) {
        float xk = x[k];
        const float* wr = &W[k * 32];   // uniform -> s_load
#pragma unroll
        for (int c = 0; c < 32; c += 4) {
            f32x4 wv = *(const f32x4*)&wr[c];
            acc[c]     += xk * wv.x;
            acc[c + 1] += xk * wv.y;
            acc[c + 2] += xk * wv.z;
            acc[c + 3] += xk * wv.w;
        }
    }
    float dv = dinv[r];
    __half2* hp = &H2[(long)r * 16];
#pragma unroll
    for (int c = 0; c < 16; c++)
        hp[c] = __floats2half2_rn(acc[2 * c] * dv, acc[2 * c + 1] * dv);
}

// ---------------- head: out = relu(x@lin1+b1)@lin2+b2, f32 out ----------------
__global__ __launch_bounds__(256) void k_head(const __half2* __restrict__ X2,
                                              const float* __restrict__ L1W,
                                              const float* __restrict__ L1B,
                                              const float* __restrict__ L2W,
                                              const float* __restrict__ L2B,
                                              float* __restrict__ out, int n) {
    int r = blockIdx.x * 256 + threadIdx.x;
    if (r >= n) return;
    float x[32];
#pragma unroll
    for (int i = 0; i < 16; i++) {
        float2 v = __half22float2(X2[(long)r * 16 + i]);
        x[2 * i] = v.x; x[2 * i + 1] = v.y;
    }
    float t1[16];
#pragma unroll
    for (int c = 0; c < 16; c++) t1[c] = L1B[c];
#pragma unroll
    for (int k = 0; k < 32; k++) {
        float xk = x[k];
        const float* wr = &L1W[k * 16];
#pragma unroll
        for (int c = 0; c < 16; c++) t1[c] += xk * wr[c];
    }
#pragma unroll
    for (int c = 0; c < 16; c++) t1[c] = fmaxf(t1[c], 0.f);
    float o[10];
#pragma unroll
    for (int c = 0; c < 10; c++) o[c] = L2B[c];
#pragma unroll
    for (int k = 0; k < 16; k++) {
        float tk = t1[k];
        const float* wr = &L2W[k * 10];
#pragma unroll
        for (int c = 0; c < 10; c++) o[c] += tk * wr[c];
    }
#pragma unroll
    for (int c = 0; c < 10; c++) out[(long)r * 10 + c] = o[c];
}

extern "C" void kernel_launch(void* const* d_in, const int* in_sizes, int n_in,
                              void* d_out, int out_size, void* d_ws, size_t ws_size,
                              hipStream_t stream) {
    const float* x0 = (const float*)d_in[0];
    const int* ei = (const int*)d_in[1];
    const float* W1 = (const float*)d_in[3];
    const float* b1 = (const float*)d_in[4];
    const float* W2 = (const float*)d_in[5];
    const float* b2 = (const float*)d_in[6];
    const float* W3 = (const float*)d_in[7];
    const float* b3 = (const float*)d_in[8];
    const float* l1W = (const float*)d_in[9];
    const float* l1b = (const float*)d_in[10];
    const float* l2W = (const float*)d_in[11];
    const float* l2b = (const float*)d_in[12];

    const int E = in_sizes[1] / 2;
    const int N = N_NODES;

    char* w = (char*)d_ws;
    // bp (25.6 MB) aliases h2+x2 (12.8 MB): bp dead before k_gemm1 writes h2.
    __half2* h2   = (__half2*)(w);                 //  6,400,000 B
    __half2* x2   = (__half2*)(w + 6400000);       //  6,400,000 B
    int2*  bp     = (int2*) (w);                   // 25,600,000 B (alias)
    int*   gh     = (int*)  (w + 25600000);        //    400,384 B
    int*   btot   = (int*)  (w + 26000384);        //      1,564 B
    int*   bbase  = (int*)  (w + 26001948);        //      1,568 B
    int*   rowptr = (int*)  (w + 26003516);        //    400,016 B
    float* dinv   = (float*)(w + 26403532);        //    400,000 B
    int*   csr    = (int*)  (w + 26803532);        // 12,800,000 B
    int*   mode   = (int*)  (w + 39603532);        //          4 B

    const int chunk = (E + HBLK - 1) / HBLK;   // 12500
    const int AGB = (N + 31) / 32;             // 3125
    const int G1B = (N + 127) / 128;           // 782
    const int NB  = (N + 255) / 256;           // 391

    // --- CSR build: zero global atomics ---
    k_detect<<<1, 256, 0, stream>>>(ei, mode);
    k_hist<<<HBLK, 256, 0, stream>>>(ei, mode, gh, E, chunk);
    k_btot<<<NBUK, 256, 0, stream>>>(gh, btot);
    k_scan_btot<<<1, 512, 0, stream>>>(btot, bbase, rowptr, E);
    k_scan_cols<<<NBUK, 256, 0, stream>>>(gh, bbase);
    k_bucketize<<<HBLK, 256, 0, stream>>>(ei, mode, gh, bp, E, chunk);
    k_build_csr<<<NBUK, 256, 0, stream>>>(bp, bbase, rowptr, dinv, csr);

    // --- layer 1 ---
    k_gemm1<<<G1B, 128, 0, stream>>>(x0, W1, dinv, h2);
    k_agg<<<AGB, 256, 0, stream>>>(h2, rowptr, csr, dinv, b1, x2, 0);
    k_agg<<<AGB, 256, 0, stream>>>(h2, rowptr, csr, dinv, b1, x2, 8);
    k_mm<<<NB, 256, 0, stream>>>(x2, W2, dinv, h2, N);
    // --- layer 2 ---
    k_agg<<<AGB, 256, 0, stream>>>(h2, rowptr, csr, dinv, b2, x2, 0);
    k_agg<<<AGB, 256, 0, stream>>>(h2, rowptr, csr, dinv, b2, x2, 8);
    k_mm<<<NB, 256, 0, stream>>>(x2, W3, dinv, h2, N);
    // --- layer 3 + head ---
    k_agg<<<AGB, 256, 0, stream>>>(h2, rowptr, csr, dinv, b3, x2, 0);
    k_agg<<<AGB, 256, 0, stream>>>(h2, rowptr, csr, dinv, b3, x2, 8);
    k_head<<<NB, 256, 0, stream>>>(x2, l1W, l1b, l2W, l2b, (float*)d_out, N);
}